// Round 4
// baseline (2078.105 us; speedup 1.0000x reference)
//
#include <hip/hip_runtime.h>
#include <cstddef>
#include <cstdint>

#define NN 200000

typedef _Float16 f16;
typedef __attribute__((ext_vector_type(8))) f16 f16x8;
typedef __attribute__((ext_vector_type(4))) float f32x4;

#define MFMA16(a, b, c) __builtin_amdgcn_mfma_f32_16x16x32_f16((a), (b), (c), 0, 0, 0)

union H8 { uint4 u; f16 f[8]; f16x8 v; };
union H4 { uint2 u; f16 f[4]; };
union F4 { float4 v; float f[4]; };

__device__ __forceinline__ float fsig(float v) {
    return __builtin_amdgcn_rcpf(1.0f + __expf(-v));
}
__device__ __forceinline__ float ftanh(float v) {
    return 1.0f - 2.0f * __builtin_amdgcn_rcpf(1.0f + __expf(2.0f * v));
}
// fp16 split-2: v = hi + lo/4096 + O(2^-22 |v|)
__device__ __forceinline__ void split2(float v, f16& hh, f16& ll) {
    hh = (f16)v; ll = (f16)((v - (float)hh) * 4096.0f);
}
// bijective XCD-chunking swizzle
__device__ __forceinline__ int xcd_swz(int bid, int nwg) {
    int q = nwg >> 3, r = nwg & 7;
    int xcd = bid & 7, i = bid >> 3;
    return (xcd < r ? xcd * (q + 1) : r * (q + 1) + (xcd - r) * q) + i;
}

// ---------------------------------------------------------------------------
// Prep kernels
// ---------------------------------------------------------------------------
__global__ void split_x_kernel(const float* __restrict__ src,
                               f16* __restrict__ hi, f16* __restrict__ lo, long n8)
{
    long i = (long)blockIdx.x * blockDim.x + threadIdx.x;
    long stride = (long)gridDim.x * blockDim.x;
    for (; i < n8; i += stride) {
        const float4* s = (const float4*)(src + i * 8);
        float4 a = s[0], b = s[1];
        float vv[8] = {a.x, a.y, a.z, a.w, b.x, b.y, b.z, b.w};
        H8 ph, pl;
#pragma unroll
        for (int j = 0; j < 8; ++j) split2(vv[j], ph.f[j], pl.f[j]);
        *(uint4*)(hi + i * 8) = ph.u;
        *(uint4*)(lo + i * 8) = pl.u;
    }
}

// weight [K][N] fp32 -> frag layout ((k>>3)*N + n)*8 + (k&7), hi/lo fp16
__global__ void split_w_kernel(const float* __restrict__ src,
                               f16* __restrict__ dh, f16* __restrict__ dl, int K, int N)
{
    int e = blockIdx.x * 256 + threadIdx.x;
    if (e >= K * N) return;
    int k = e / N, n = e - k * N;
    f16 hh, ll; split2(src[e], hh, ll);
    int o = ((k >> 3) * N + n) * 8 + (k & 7);
    dh[o] = hh; dl[o] = ll;
}

// ---------------------------------------------------------------------------
// Parent kernel, LDS-free, swapped operands: D[d][node].
// Block = 64 nodes x 192 d (ct picks 64-of-256 d per gate). Wave w: 16 nodes.
// iou = x@W_iou + ht@U_iou + b_iou -> c,h (+ split h, + ht for level above).
// ---------------------------------------------------------------------------
template<bool USE_HT, bool HAS_PAR>
__launch_bounds__(256, 2)
__global__ void parent_k(const f16* __restrict__ x_hi, const f16* __restrict__ x_lo,
                         const f16* __restrict__ wih, const f16* __restrict__ wil,
                         const f16* __restrict__ uih, const f16* __restrict__ uil,
                         const float* __restrict__ b_iou,
                         const float* __restrict__ fcR,
                         const f16* __restrict__ hthR, const f16* __restrict__ htlR,
                         float* __restrict__ cW, float* __restrict__ hW,
                         f16* __restrict__ h_hi, f16* __restrict__ h_lo,
                         f16* __restrict__ hthW, f16* __restrict__ htlW,
                         int ps, int pe, int ps_par)
{
    const int work = xcd_swz(blockIdx.x, gridDim.x);
    const int rt = work >> 2, ct = work & 3;
    const int t = threadIdx.x, lane = t & 63, w = t >> 6;
    const int c15 = lane & 15, qq = lane >> 4;
    const int node = ps + rt * 64 + w * 16 + c15;
    const bool nv = node < pe;
    const bool hok = USE_HT && nv && (node <= 24999);   // has children

    f32x4 accH[12], accL[12];
#pragma unroll
    for (int i = 0; i < 12; ++i) { accH[i] = (f32x4){0,0,0,0}; accL[i] = (f32x4){0,0,0,0}; }

    const size_t bx  = (size_t)node * 256 + qq * 8;
    const size_t bht = (size_t)(node - ps) * 256 + qq * 8;
    const int KT = USE_HT ? 512 : 256;

#pragma unroll 2
    for (int k0 = 0; k0 < KT; k0 += 32) {
        H8 bh, bl; bh.u = (uint4){0,0,0,0}; bl.u = (uint4){0,0,0,0};
        if (k0 < 256) {
            if (nv) { bh.u = *(const uint4*)(x_hi + bx + k0);
                      bl.u = *(const uint4*)(x_lo + bx + k0); }
        } else {
            if (hok) { bh.u = *(const uint4*)(hthR + bht + (k0 - 256));
                       bl.u = *(const uint4*)(htlR + bht + (k0 - 256)); }
        }
        const f16* Ah = (k0 < 256) ? wih : uih;
        const f16* Al = (k0 < 256) ? wil : uil;
        const size_t kb = ((k0 & 255) >> 3) + qq;
#pragma unroll
        for (int nf = 0; nf < 12; ++nf) {
            const size_t ao = (kb * 768 + (size_t)((nf >> 2) * 256 + ct * 64 + (nf & 3) * 16 + c15)) * 8;
            f16x8 ah = *(const f16x8*)(Ah + ao);
            f16x8 al = *(const f16x8*)(Al + ao);
            accH[nf] = MFMA16(ah, bh.v, accH[nf]);
            accL[nf] = MFMA16(ah, bl.v, accL[nf]);
            accL[nf] = MFMA16(al, bh.v, accL[nf]);
        }
    }

    const float INV = 1.0f / 4096.0f;
    const size_t no = (size_t)node * 256;
#pragma unroll
    for (int n = 0; n < 4; ++n) {
        const int d0 = ct * 64 + n * 16 + qq * 4;
        F4 bi, bo, bu, fcv, cn, hn;
        bi.v = *(const float4*)(b_iou + d0);
        bo.v = *(const float4*)(b_iou + 256 + d0);
        bu.v = *(const float4*)(b_iou + 512 + d0);
        fcv.v = (float4){0, 0, 0, 0};
        if (hok) fcv.v = *(const float4*)(fcR + (size_t)(node - ps) * 256 + d0);
#pragma unroll
        for (int j = 0; j < 4; ++j) {
            if (nv) {
                float ig = accH[n][j]     + accL[n][j]     * INV + bi.f[j];
                float og = accH[4 + n][j] + accL[4 + n][j] * INV + bo.f[j];
                float ug = accH[8 + n][j] + accL[8 + n][j] * INV + bu.f[j];
                cn.f[j] = fsig(ig) * ftanh(ug) + fcv.f[j];
                hn.f[j] = fsig(og) * ftanh(cn.f[j]);
            } else { cn.f[j] = 0.f; hn.f[j] = 0.f; }
        }
        if (nv) {
            *(float4*)(cW + no + d0) = cn.v;
            *(float4*)(hW + no + d0) = hn.v;
            H4 sh, sl;
#pragma unroll
            for (int j = 0; j < 4; ++j) split2(hn.f[j], sh.f[j], sl.f[j]);
            *(uint2*)(h_hi + no + d0) = sh.u;
            *(uint2*)(h_lo + no + d0) = sl.u;
        }
        if (HAS_PAR) {
            // sibling-group h-sum: groups of 8 nodes == c15 groups (levels start at 1 mod 8)
            F4 s = hn;
#pragma unroll
            for (int j = 0; j < 4; ++j) {
                s.f[j] += __shfl_xor(s.f[j], 1);
                s.f[j] += __shfl_xor(s.f[j], 2);
                s.f[j] += __shfl_xor(s.f[j], 4);
            }
            if (((c15 & 7) == 0) && nv) {
                const int par = (node - 1) >> 3;
                const size_t o = (size_t)(par - ps_par) * 256 + d0;
                H4 sh, sl;
#pragma unroll
                for (int j = 0; j < 4; ++j) split2(s.f[j], sh.f[j], sl.f[j]);
                *(uint2*)(hthW + o) = sh.u;
                *(uint2*)(htlW + o) = sl.u;
            }
        }
    }
}

// ---------------------------------------------------------------------------
// Child kernel, LDS-free, swapped operands: D[d][child].
// Block = 64 children x 128 d (ct in {0,1}). f = sigm(x[par]@W_f + h@U_f + b_f);
// epilogue: fc[par] = sum_siblings f*c  (shfl reduce over c15 groups of 8).
// ---------------------------------------------------------------------------
__launch_bounds__(256, 2)
__global__ void child_k(const f16* __restrict__ x_hi, const f16* __restrict__ x_lo,
                        const f16* __restrict__ h_hi, const f16* __restrict__ h_lo,
                        const f16* __restrict__ wfh, const f16* __restrict__ wfl,
                        const f16* __restrict__ ufh, const f16* __restrict__ ufl,
                        const float* __restrict__ b_f,
                        const float* __restrict__ cS,
                        float* __restrict__ fcW,
                        int cs, int ce, int ps)
{
    const int work = xcd_swz(blockIdx.x, gridDim.x);
    const int rt = work >> 1, ct = work & 1;
    const int t = threadIdx.x, lane = t & 63, w = t >> 6;
    const int c15 = lane & 15, qq = lane >> 4;
    const int child = cs + rt * 64 + w * 16 + c15;
    const bool cv = child < ce;

    f32x4 accH[8], accL[8];
#pragma unroll
    for (int i = 0; i < 8; ++i) { accH[i] = (f32x4){0,0,0,0}; accL[i] = (f32x4){0,0,0,0}; }

    const size_t bx = (size_t)((child - 1) >> 3) * 256 + qq * 8;
    const size_t bh_ = (size_t)child * 256 + qq * 8;

#pragma unroll 2
    for (int k0 = 0; k0 < 512; k0 += 32) {
        H8 bh, bl; bh.u = (uint4){0,0,0,0}; bl.u = (uint4){0,0,0,0};
        if (cv) {
            if (k0 < 256) { bh.u = *(const uint4*)(x_hi + bx + k0);
                            bl.u = *(const uint4*)(x_lo + bx + k0); }
            else          { bh.u = *(const uint4*)(h_hi + bh_ + (k0 - 256));
                            bl.u = *(const uint4*)(h_lo + bh_ + (k0 - 256)); }
        }
        const f16* Ah = (k0 < 256) ? wfh : ufh;
        const f16* Al = (k0 < 256) ? wfl : ufl;
        const size_t kb = ((k0 & 255) >> 3) + qq;
#pragma unroll
        for (int nf = 0; nf < 8; ++nf) {
            const size_t ao = (kb * 256 + (size_t)(ct * 128 + nf * 16 + c15)) * 8;
            f16x8 ah = *(const f16x8*)(Ah + ao);
            f16x8 al = *(const f16x8*)(Al + ao);
            accH[nf] = MFMA16(ah, bh.v, accH[nf]);
            accL[nf] = MFMA16(ah, bl.v, accL[nf]);
            accL[nf] = MFMA16(al, bh.v, accL[nf]);
        }
    }

    const float INV = 1.0f / 4096.0f;
#pragma unroll
    for (int nf = 0; nf < 8; ++nf) {
        const int d0 = ct * 128 + nf * 16 + qq * 4;
        F4 bf, cq, fcq;
        bf.v = *(const float4*)(b_f + d0);
        cq.v = (float4){0, 0, 0, 0};
        if (cv) cq.v = *(const float4*)(cS + (size_t)child * 256 + d0);
#pragma unroll
        for (int j = 0; j < 4; ++j) {
            float pre = accH[nf][j] + accL[nf][j] * INV + bf.f[j];
            fcq.f[j] = cv ? fsig(pre) * cq.f[j] : 0.f;
        }
#pragma unroll
        for (int j = 0; j < 4; ++j) {
            fcq.f[j] += __shfl_xor(fcq.f[j], 1);
            fcq.f[j] += __shfl_xor(fcq.f[j], 2);
            fcq.f[j] += __shfl_xor(fcq.f[j], 4);
        }
        if (((c15 & 7) == 0) && cv) {
            const size_t o = (size_t)(((child - 1) >> 3) - ps) * 256 + d0;
            *(float4*)(fcW + o) = fcq.v;
        }
    }
}

// ---------------------------------------------------------------------------

extern "C" void kernel_launch(void* const* d_in, const int* in_sizes, int n_in,
                              void* d_out, int out_size, void* d_ws, size_t ws_size,
                              hipStream_t stream)
{
    const float* x     = (const float*)d_in[0];
    const float* W_iou = (const float*)d_in[1];
    const float* U_iou = (const float*)d_in[2];
    const float* b_iou = (const float*)d_in[3];
    const float* W_f   = (const float*)d_in[4];
    const float* U_f   = (const float*)d_in[5];
    const float* b_f   = (const float*)d_in[6];

    float* h = (float*)d_out;

    char* p = (char*)d_ws;
    float* c   = (float*)p;  p += (size_t)NN * 256 * 4;
    float* fc  = (float*)p;  p += (size_t)20320 * 256 * 4;
    f16* hthA = (f16*)p;     p += (size_t)20320 * 256 * 2;
    f16* htlA = (f16*)p;     p += (size_t)20320 * 256 * 2;
    f16* wfh = (f16*)p;      p += 65536 * 2;
    f16* wfl = (f16*)p;      p += 65536 * 2;
    f16* ufh = (f16*)p;      p += 65536 * 2;
    f16* ufl = (f16*)p;      p += 65536 * 2;
    f16* wih = (f16*)p;      p += 196608 * 2;
    f16* wil = (f16*)p;      p += 196608 * 2;
    f16* uih = (f16*)p;      p += 196608 * 2;
    f16* uil = (f16*)p;      p += 196608 * 2;
    f16* x_hi = (f16*)p;     p += (size_t)NN * 256 * 2;
    f16* x_lo = (f16*)p;     p += (size_t)NN * 256 * 2;
    f16* h_hi = (f16*)p;     p += (size_t)NN * 256 * 2;
    f16* h_lo = (f16*)p;     p += (size_t)NN * 256 * 2;

    // ht ping-pong slots (<=4096 rows each) carved from the leaf region of
    // h_hi/h_lo, which is dead after the level-5 child kernel has run.
    f16* slh[2] = { h_hi + (size_t)37449 * 256, h_hi + (size_t)(37449 + 4096) * 256 };
    f16* sll[2] = { h_lo + (size_t)37449 * 256, h_lo + (size_t)(37449 + 4096) * 256 };

    split_w_kernel<<<256, 256, 0, stream>>>(W_f,   wfh, wfl, 256, 256);
    split_w_kernel<<<256, 256, 0, stream>>>(U_f,   ufh, ufl, 256, 256);
    split_w_kernel<<<768, 256, 0, stream>>>(W_iou, wih, wil, 256, 768);
    split_w_kernel<<<768, 256, 0, stream>>>(U_iou, uih, uil, 256, 768);
    split_x_kernel<<<4096, 256, 0, stream>>>(x, x_hi, x_lo, (long)NN * 256 / 8);

    const int S_[8] = {0, 1, 9, 73, 585, 4681, 37449, 200000};

    // leaves (level 6): no ht input; writes ht for level-5 parents into A-buffer
    {
        int np = S_[7] - S_[6];
        int grid = ((np + 63) / 64) * 4;
        parent_k<false, true><<<grid, 256, 0, stream>>>(
            x_hi, x_lo, wih, wil, uih, uil, b_iou,
            nullptr, nullptr, nullptr, c, h, h_hi, h_lo,
            hthA, htlA, S_[6], S_[7], S_[5]);
    }

    const f16* rdh = hthA; const f16* rdl = htlA;
    int sl = 0;
    for (int l = 5; l >= 0; --l) {
        int ps = S_[l], pe = S_[l + 1], np = pe - ps;
        int cs = S_[l + 1], ce = S_[l + 2], nch = ce - cs;
        int cgrid = ((nch + 63) / 64) * 2;
        int pgrid = ((np + 63) / 64) * 4;

        child_k<<<cgrid, 256, 0, stream>>>(
            x_hi, x_lo, h_hi, h_lo, wfh, wfl, ufh, ufl, b_f, c, fc, cs, ce, ps);

        if (l > 0) {
            parent_k<true, true><<<pgrid, 256, 0, stream>>>(
                x_hi, x_lo, wih, wil, uih, uil, b_iou,
                fc, rdh, rdl, c, h, h_hi, h_lo,
                slh[sl], sll[sl], ps, pe, S_[l - 1]);
            rdh = slh[sl]; rdl = sll[sl]; sl ^= 1;
        } else {
            parent_k<true, false><<<pgrid, 256, 0, stream>>>(
                x_hi, x_lo, wih, wil, uih, uil, b_iou,
                fc, rdh, rdl, c, h, h_hi, h_lo,
                nullptr, nullptr, ps, pe, 0);
        }
    }
}

// Round 5
// 1405.485 us; speedup vs baseline: 1.4786x; 1.4786x over previous
//
#include <hip/hip_runtime.h>
#include <cstddef>
#include <cstdint>

#define NN 200000
#define NINT 25000   // nodes 0..24999 have children

typedef _Float16 f16;
typedef __attribute__((ext_vector_type(8))) f16 f16x8;
typedef __attribute__((ext_vector_type(4))) float f32x4;

#define MFMA16(a, b, c) __builtin_amdgcn_mfma_f32_16x16x32_f16((a), (b), (c), 0, 0, 0)

union H8 { uint4 u; f16 f[8]; f16x8 v; };
union H4 { uint2 u; f16 f[4]; };
union F4 { float4 v; float f[4]; };

__device__ __forceinline__ float fsig(float v)  { return __builtin_amdgcn_rcpf(1.0f + __expf(-v)); }
__device__ __forceinline__ float ftanh(float v) { return 1.0f - 2.0f * __builtin_amdgcn_rcpf(1.0f + __expf(2.0f * v)); }
__device__ __forceinline__ void split2(float v, f16& hh, f16& ll) {
    hh = (f16)v; ll = (f16)((v - (float)hh) * 4096.0f);
}

// ---------------------------------------------------------------------------
// Prep kernels
// ---------------------------------------------------------------------------
__global__ void split_x_kernel(const float* __restrict__ src,
                               f16* __restrict__ hi, f16* __restrict__ lo, long n8)
{
    long i = (long)blockIdx.x * blockDim.x + threadIdx.x;
    long stride = (long)gridDim.x * blockDim.x;
    for (; i < n8; i += stride) {
        const float4* s = (const float4*)(src + i * 8);
        float4 a = s[0], b = s[1];
        float vv[8] = {a.x, a.y, a.z, a.w, b.x, b.y, b.z, b.w};
        H8 ph, pl;
#pragma unroll
        for (int j = 0; j < 8; ++j) split2(vv[j], ph.f[j], pl.f[j]);
        *(uint4*)(hi + i * 8) = ph.u;
        *(uint4*)(lo + i * 8) = pl.u;
    }
}

// weight [K][N] fp32 -> frag layout ((k>>3)*N + n)*8 + (k&7), hi/lo fp16
__global__ void split_w_kernel(const float* __restrict__ src,
                               f16* __restrict__ dh, f16* __restrict__ dl, int K, int N)
{
    int e = blockIdx.x * 256 + threadIdx.x;
    if (e >= K * N) return;
    int k = e / N, n = e - k * N;
    f16 hh, ll; split2(src[e], hh, ll);
    int o = ((k >> 3) * N + n) * 8 + (k & 7);
    dh[o] = hh; dl[o] = ll;
}

// ---------------------------------------------------------------------------
// iou_k: K=256 GEMM vs W_iou/U_iou with resident weights.
//   MODE 0: childless nodes. B = x-split[node]. Epilogue: full LSTM (fc=0)
//           -> c, h(d_out), h-split.
//   MODE 1: x_iou precompute. B = x-split[node]. Store acc + b_iou.
//   MODE 2: internal parents. B = ht-split[node-base]. Epilogue: full LSTM
//           with x_iou[node] + fc[node-base] -> c, h, h-split.
// Block: 4 waves, each owns cols {g*256 + ct*64 + w*16 .. +16} for g=0..2.
// Tile: 16 nodes. Persistent: m = xcd + 8*(s + ns*j).
// ---------------------------------------------------------------------------
template<int MODE>
__launch_bounds__(256, 1)
__global__ void iou_k(const f16* __restrict__ bsh, const f16* __restrict__ bsl,
                      const f16* __restrict__ wh, const f16* __restrict__ wl,
                      const float* __restrict__ b_iou,
                      const float* __restrict__ xiR, const float* __restrict__ fcR,
                      float* __restrict__ xiW,
                      float* __restrict__ cW, float* __restrict__ hW,
                      f16* __restrict__ h_hi, f16* __restrict__ h_lo,
                      int base, int pe, int ntiles, int ns)
{
    const int g = blockIdx.x;
    const int xcd = g & 7, r = g >> 3;
    const int ct = r & 3, s = r >> 2;
    const int t = threadIdx.x, lane = t & 63, w = t >> 6;
    const int c15 = lane & 15, qq = lane >> 4;
    const float INV = 1.0f / 4096.0f;

    // resident weights: 3 gates x 8 chunks x (hi+lo) = 192 VGPR
    f16x8 wH[3][8], wL[3][8];
#pragma unroll
    for (int gt = 0; gt < 3; ++gt) {
        const int col = gt * 256 + ct * 64 + w * 16 + c15;
#pragma unroll
        for (int ch = 0; ch < 8; ++ch) {
            const size_t ao = ((size_t)(ch * 4 + qq) * 768 + col) * 8;
            wH[gt][ch] = *(const f16x8*)(wh + ao);
            wL[gt][ch] = *(const f16x8*)(wl + ao);
        }
    }

    const int d0 = ct * 64 + w * 16 + qq * 4;
    F4 b0, b1, b2;
    if (MODE != 2) {
        b0.v = *(const float4*)(b_iou + d0);
        b1.v = *(const float4*)(b_iou + 256 + d0);
        b2.v = *(const float4*)(b_iou + 512 + d0);
    }

    for (int j = 0; ; ++j) {
        const int m = xcd + 8 * (s + ns * j);
        if (m >= ntiles) break;
        const int node = base + m * 16 + c15;
        const bool nv = node < pe;

        f32x4 aH[3], aL[3];
#pragma unroll
        for (int gt = 0; gt < 3; ++gt) { aH[gt] = (f32x4){0,0,0,0}; aL[gt] = (f32x4){0,0,0,0}; }

        const size_t bo = (MODE == 2)
            ? (size_t)(node - base) * 256 + qq * 8
            : (size_t)node * 256 + qq * 8;
#pragma unroll
        for (int ch = 0; ch < 8; ++ch) {
            H8 bh, bl; bh.u = (uint4){0,0,0,0}; bl.u = (uint4){0,0,0,0};
            if (nv) {
                bh.u = *(const uint4*)(bsh + bo + ch * 32);
                bl.u = *(const uint4*)(bsl + bo + ch * 32);
            }
#pragma unroll
            for (int gt = 0; gt < 3; ++gt) {
                aH[gt] = MFMA16(wH[gt][ch], bh.v, aH[gt]);
                aL[gt] = MFMA16(wH[gt][ch], bl.v, aL[gt]);
                aL[gt] = MFMA16(wL[gt][ch], bh.v, aL[gt]);
            }
        }

        if (MODE == 1) {
            if (nv) {
                float* xo = xiW + (size_t)node * 768 + d0;
                F4 o0, o1, o2;
#pragma unroll
                for (int jj = 0; jj < 4; ++jj) {
                    o0.f[jj] = aH[0][jj] + aL[0][jj] * INV + b0.f[jj];
                    o1.f[jj] = aH[1][jj] + aL[1][jj] * INV + b1.f[jj];
                    o2.f[jj] = aH[2][jj] + aL[2][jj] * INV + b2.f[jj];
                }
                *(float4*)(xo)       = o0.v;
                *(float4*)(xo + 256) = o1.v;
                *(float4*)(xo + 512) = o2.v;
            }
        } else {
            F4 xi0, xi1, xi2, fcv;
            if (MODE == 0) {
                xi0 = b0; xi1 = b1; xi2 = b2; fcv.v = (float4){0,0,0,0};
            } else {
                xi0.v = (float4){0,0,0,0}; xi1 = xi0; xi2 = xi0; fcv = xi0;
                if (nv) {
                    const float* xr = xiR + (size_t)node * 768;
                    xi0.v = *(const float4*)(xr + d0);
                    xi1.v = *(const float4*)(xr + 256 + d0);
                    xi2.v = *(const float4*)(xr + 512 + d0);
                    fcv.v = *(const float4*)(fcR + (size_t)(node - base) * 256 + d0);
                }
            }
            F4 cn, hn; H4 sh, sl;
#pragma unroll
            for (int jj = 0; jj < 4; ++jj) {
                float ig = aH[0][jj] + aL[0][jj] * INV + xi0.f[jj];
                float og = aH[1][jj] + aL[1][jj] * INV + xi1.f[jj];
                float ug = aH[2][jj] + aL[2][jj] * INV + xi2.f[jj];
                float cc = fsig(ig) * ftanh(ug) + fcv.f[jj];
                float hh = fsig(og) * ftanh(cc);
                cn.f[jj] = cc; hn.f[jj] = hh;
                split2(hh, sh.f[jj], sl.f[jj]);
            }
            if (nv) {
                const size_t o = (size_t)node * 256 + d0;
                *(float4*)(cW + o) = cn.v;
                *(float4*)(hW + o) = hn.v;
                *(uint2*)(h_hi + o) = sh.u;
                *(uint2*)(h_lo + o) = sl.u;
            }
        }
    }
}

// ---------------------------------------------------------------------------
// f_k: K=256 GEMM vs W_f/U_f with resident weights.
//   MODE 0: xf precompute. B = x-split[node], nodes 0..24999. Store acc+b_f.
//   MODE 1: child pass. B = h-split[node]. Epilogue: f = sigm(acc + xf[par]);
//           fc = shfl-sum f*c; ht = shfl-sum h -> split.
// Block: 4 waves, wave owns 32 cols (nf=0,1): col = ct*128 + w*32 + nf*16.
// Tile: 32 nodes (mm=0,1). Persistent: m = xcd + 8*(s + ns*j).
// ---------------------------------------------------------------------------
template<int MODE>
__launch_bounds__(256, 1)
__global__ void f_k(const f16* __restrict__ bsh, const f16* __restrict__ bsl,
                    const f16* __restrict__ wh, const f16* __restrict__ wl,
                    const float* __restrict__ b_f,
                    const float* __restrict__ xfR, const float* __restrict__ cR,
                    float* __restrict__ xfW,
                    float* __restrict__ fcW, f16* __restrict__ hthW, f16* __restrict__ htlW,
                    int base, int ce, int pp, int ntiles, int ns)
{
    const int g = blockIdx.x;
    const int xcd = g & 7, r = g >> 3;
    const int ct = r & 1, s = r >> 1;
    const int t = threadIdx.x, lane = t & 63, w = t >> 6;
    const int c15 = lane & 15, qq = lane >> 4;
    const float INV = 1.0f / 4096.0f;

    // resident weights: 2 nf x 8 chunks x (hi+lo) = 128 VGPR
    f16x8 wH[2][8], wL[2][8];
#pragma unroll
    for (int nf = 0; nf < 2; ++nf) {
        const int col = ct * 128 + w * 32 + nf * 16 + c15;
#pragma unroll
        for (int ch = 0; ch < 8; ++ch) {
            const size_t ao = ((size_t)(ch * 4 + qq) * 256 + col) * 8;
            wH[nf][ch] = *(const f16x8*)(wh + ao);
            wL[nf][ch] = *(const f16x8*)(wl + ao);
        }
    }

    F4 bf[2];
    if (MODE == 0) {
#pragma unroll
        for (int nf = 0; nf < 2; ++nf)
            bf[nf].v = *(const float4*)(b_f + ct * 128 + w * 32 + nf * 16 + qq * 4);
    }

    for (int j = 0; ; ++j) {
        const int m = xcd + 8 * (s + ns * j);
        if (m >= ntiles) break;
        const int n0 = base + m * 32 + c15;
        const int n1 = n0 + 16;
        const bool v0 = n0 < ce, v1 = n1 < ce;

        f32x4 aH[2][2], aL[2][2];
#pragma unroll
        for (int nf = 0; nf < 2; ++nf)
#pragma unroll
            for (int mm = 0; mm < 2; ++mm) { aH[nf][mm] = (f32x4){0,0,0,0}; aL[nf][mm] = (f32x4){0,0,0,0}; }

        const size_t bo0 = (size_t)n0 * 256 + qq * 8;
        const size_t bo1 = (size_t)n1 * 256 + qq * 8;
#pragma unroll
        for (int ch = 0; ch < 8; ++ch) {
            H8 bh0, bl0, bh1, bl1;
            bh0.u = (uint4){0,0,0,0}; bl0.u = bh0.u; bh1.u = bh0.u; bl1.u = bh0.u;
            if (v0) { bh0.u = *(const uint4*)(bsh + bo0 + ch * 32);
                      bl0.u = *(const uint4*)(bsl + bo0 + ch * 32); }
            if (v1) { bh1.u = *(const uint4*)(bsh + bo1 + ch * 32);
                      bl1.u = *(const uint4*)(bsl + bo1 + ch * 32); }
#pragma unroll
            for (int nf = 0; nf < 2; ++nf) {
                aH[nf][0] = MFMA16(wH[nf][ch], bh0.v, aH[nf][0]);
                aL[nf][0] = MFMA16(wH[nf][ch], bl0.v, aL[nf][0]);
                aL[nf][0] = MFMA16(wL[nf][ch], bh0.v, aL[nf][0]);
                aH[nf][1] = MFMA16(wH[nf][ch], bh1.v, aH[nf][1]);
                aL[nf][1] = MFMA16(wH[nf][ch], bl1.v, aL[nf][1]);
                aL[nf][1] = MFMA16(wL[nf][ch], bh1.v, aL[nf][1]);
            }
        }

#pragma unroll
        for (int mm = 0; mm < 2; ++mm) {
            const int node = mm ? n1 : n0;
            const bool nv = mm ? v1 : v0;
            const int par = (node - 1) >> 3;
#pragma unroll
            for (int nf = 0; nf < 2; ++nf) {
                const int d0 = ct * 128 + w * 32 + nf * 16 + qq * 4;
                if (MODE == 0) {
                    if (nv) {
                        F4 o;
#pragma unroll
                        for (int jj = 0; jj < 4; ++jj)
                            o.f[jj] = aH[nf][mm][jj] + aL[nf][mm][jj] * INV + bf[nf].f[jj];
                        *(float4*)(xfW + (size_t)node * 256 + d0) = o.v;
                    }
                } else {
                    F4 xf4, c4, h4, fcq, htq;
                    xf4.v = (float4){0,0,0,0}; c4 = xf4; h4 = xf4;
                    if (nv) {
                        xf4.v = *(const float4*)(xfR + (size_t)par * 256 + d0);
                        c4.v  = *(const float4*)(cR + (size_t)node * 256 + d0);
                        H4 hh, hl;
                        hh.u = *(const uint2*)(bsh + (size_t)node * 256 + d0);
                        hl.u = *(const uint2*)(bsl + (size_t)node * 256 + d0);
#pragma unroll
                        for (int jj = 0; jj < 4; ++jj)
                            h4.f[jj] = (float)hh.f[jj] + (float)hl.f[jj] * INV;
                    }
#pragma unroll
                    for (int jj = 0; jj < 4; ++jj) {
                        float f = fsig(aH[nf][mm][jj] + aL[nf][mm][jj] * INV + xf4.f[jj]);
                        fcq.f[jj] = nv ? f * c4.f[jj] : 0.f;
                        htq.f[jj] = nv ? h4.f[jj] : 0.f;
                    }
#pragma unroll
                    for (int jj = 0; jj < 4; ++jj) {
                        fcq.f[jj] += __shfl_xor(fcq.f[jj], 1);
                        fcq.f[jj] += __shfl_xor(fcq.f[jj], 2);
                        fcq.f[jj] += __shfl_xor(fcq.f[jj], 4);
                        htq.f[jj] += __shfl_xor(htq.f[jj], 1);
                        htq.f[jj] += __shfl_xor(htq.f[jj], 2);
                        htq.f[jj] += __shfl_xor(htq.f[jj], 4);
                    }
                    if (((c15 & 7) == 0) && nv) {
                        const size_t o = (size_t)(par - pp) * 256 + d0;
                        *(float4*)(fcW + o) = fcq.v;
                        H4 sh, sl;
#pragma unroll
                        for (int jj = 0; jj < 4; ++jj) split2(htq.f[jj], sh.f[jj], sl.f[jj]);
                        *(uint2*)(hthW + o) = sh.u;
                        *(uint2*)(htlW + o) = sl.u;
                    }
                }
            }
        }
    }
}

// ---------------------------------------------------------------------------

extern "C" void kernel_launch(void* const* d_in, const int* in_sizes, int n_in,
                              void* d_out, int out_size, void* d_ws, size_t ws_size,
                              hipStream_t stream)
{
    const float* x     = (const float*)d_in[0];
    const float* W_iou = (const float*)d_in[1];
    const float* U_iou = (const float*)d_in[2];
    const float* b_iou = (const float*)d_in[3];
    const float* W_f   = (const float*)d_in[4];
    const float* U_f   = (const float*)d_in[5];
    const float* b_f   = (const float*)d_in[6];

    float* h = (float*)d_out;

    char* p = (char*)d_ws;
    float* c   = (float*)p;  p += (size_t)NN * 256 * 4;
    float* fc  = (float*)p;  p += (size_t)20320 * 256 * 4;
    f16* hth = (f16*)p;      p += (size_t)20320 * 256 * 2;
    f16* htl = (f16*)p;      p += (size_t)20320 * 256 * 2;
    f16* wfh = (f16*)p;      p += 65536 * 2;
    f16* wfl = (f16*)p;      p += 65536 * 2;
    f16* ufh = (f16*)p;      p += 65536 * 2;
    f16* ufl = (f16*)p;      p += 65536 * 2;
    f16* wih = (f16*)p;      p += 196608 * 2;
    f16* wil = (f16*)p;      p += 196608 * 2;
    f16* uih = (f16*)p;      p += 196608 * 2;
    f16* uil = (f16*)p;      p += 196608 * 2;
    f16* x_hi = (f16*)p;     p += (size_t)NN * 256 * 2;
    f16* x_lo = (f16*)p;     p += (size_t)NN * 256 * 2;
    f16* h_hi = (f16*)p;     p += (size_t)NN * 256 * 2;
    f16* h_lo = (f16*)p;     p += (size_t)NN * 256 * 2;
    // xf / x_iou live in the leaf region of x_lo / x_hi (dead after pass A,
    // which runs before they are written):
    float* xf    = (float*)(x_lo + (size_t)NINT * 256);   // 25000 x 256 f32
    float* x_iou = (float*)(x_hi + (size_t)NINT * 256);   // 25000 x 768 f32

    // ---- prep ----
    split_w_kernel<<<256, 256, 0, stream>>>(W_f,   wfh, wfl, 256, 256);
    split_w_kernel<<<256, 256, 0, stream>>>(U_f,   ufh, ufl, 256, 256);
    split_w_kernel<<<768, 256, 0, stream>>>(W_iou, wih, wil, 256, 768);
    split_w_kernel<<<768, 256, 0, stream>>>(U_iou, uih, uil, 256, 768);
    split_x_kernel<<<4096, 256, 0, stream>>>(x, x_hi, x_lo, (long)NN * 256 / 8);

    const int S_[8] = {0, 1, 9, 73, 585, 4681, 37449, 200000};
    auto cdiv = [](int a, int b) { return (a + b - 1) / b; };

    // ---- A: all childless nodes (25000..199999), uses x-split ----
    {
        int nt = cdiv(NN - NINT, 16);
        int ns = 64;
        iou_k<0><<<32 * ns, 256, 0, stream>>>(x_hi, x_lo, wih, wil, b_iou,
            nullptr, nullptr, nullptr, c, h, h_hi, h_lo, NINT, NN, nt, ns);
    }
    // ---- P1: xf = x@W_f + b_f for internal nodes (writes into x_lo leaf region) ----
    {
        int nt = cdiv(NINT, 32);
        int ns = (nt + 7) / 8; if (ns > 128) ns = 128; if (ns < 1) ns = 1;
        f_k<0><<<16 * ns, 256, 0, stream>>>(x_hi, x_lo, wfh, wfl, b_f,
            nullptr, nullptr, xf, nullptr, nullptr, nullptr, 0, NINT, 0, nt, ns);
    }
    // ---- P2: x_iou = x@W_iou + b_iou for internal nodes (into x_hi leaf region) ----
    {
        int nt = cdiv(NINT, 16);
        int ns = (nt + 7) / 8; if (ns > 64) ns = 64; if (ns < 1) ns = 1;
        iou_k<1><<<32 * ns, 256, 0, stream>>>(x_hi, x_lo, wih, wil, b_iou,
            nullptr, nullptr, x_iou, nullptr, nullptr, nullptr, nullptr, 0, NINT, nt, ns);
    }
    // ---- levels 5..0: child pass (fc, ht) then internal-parent pass ----
    for (int l = 5; l >= 0; --l) {
        int ps = S_[l];
        int pe = (S_[l + 1] < NINT) ? S_[l + 1] : NINT;
        int cs = S_[l + 1], ce = S_[l + 2];

        int ntc = cdiv(ce - cs, 32);
        int nsc = (ntc + 7) / 8; if (nsc > 128) nsc = 128; if (nsc < 1) nsc = 1;
        f_k<1><<<16 * nsc, 256, 0, stream>>>(h_hi, h_lo, ufh, ufl, b_f,
            xf, c, nullptr, fc, hth, htl, cs, ce, ps, ntc, nsc);

        int ntp = cdiv(pe - ps, 16);
        int nsp = (ntp + 7) / 8; if (nsp > 64) nsp = 64; if (nsp < 1) nsp = 1;
        iou_k<2><<<32 * nsp, 256, 0, stream>>>(hth, htl, uih, uil, b_iou,
            x_iou, fc, nullptr, c, h, h_hi, h_lo, ps, pe, ntp, nsp);
    }
}